// Round 1
// 214.328 us; speedup vs baseline: 1.1335x; 1.1335x over previous
//
#include <hip/hip_runtime.h>

typedef _Float16 f16;
typedef _Float16 f16x4 __attribute__((ext_vector_type(4)));
typedef _Float16 f16x8 __attribute__((ext_vector_type(8)));
typedef float f32x4  __attribute__((ext_vector_type(4)));

#define MFMAH(a, b, c) __builtin_amdgcn_mfma_f32_16x16x32_f16(a, b, c, 0, 0, 0)
#define EX2(x) __builtin_amdgcn_exp2f(x)

constexpr int D = 256;
constexpr int S = 4096;
constexpr int BATCH = 4;
constexpr int NROWS = BATCH * S;           // 16384
// softmax runs in exp2 domain: fold log2(e) into the Q scale.
constexpr float SCALE = 0.0625f * 1.44269504088896340736f;
constexpr float DTHR = 6.0f;               // defer-max threshold (log2 units): p <= 64
constexpr size_t NE = (size_t)NROWS * D;   // 4.19M elems

// async global->LDS: per-lane src addr, wave-uniform LDS base (+lane*16 by HW)
__device__ __forceinline__ void gll16(const void* g, void* l) {
  __builtin_amdgcn_global_load_lds(
      (const __attribute__((address_space(1))) unsigned int*)g,
      (__attribute__((address_space(3))) unsigned int*)l, 16, 0, 0);
}

// ---------------------------------------------------------------------------
// Prep: Wt[m][n][k] = w_m[k][n] fp16. Write-coalesced (scattered reads L2-ok).
// ---------------------------------------------------------------------------
__global__ __launch_bounds__(256)
void prep_wt_kernel(const float* __restrict__ wq, const float* __restrict__ wk,
                    const float* __restrict__ wv, const float* __restrict__ wo,
                    f16* __restrict__ Wt)
{
  const int m = blockIdx.y;
  const float* w = (m == 0) ? wq : (m == 1) ? wk : (m == 2) ? wv : wo;
  int id = blockIdx.x * 256 + threadIdx.x;    // 0..65535
  int n = id >> 8, k = id & 255;
  Wt[((size_t)m << 16) + n * 256 + k] = (f16)w[k * 256 + n];
}

// ---------------------------------------------------------------------------
// QKV projection via MFMA with LDS-staged B tiles (dbuf, gll16) and
// LDS-transposed coalesced epilogues (r7-validated layouts).
// Q: row-major fp16, scaled by SCALE (exp2-domain softmax downstream).
// ---------------------------------------------------------------------------
__global__ __launch_bounds__(256)
void qkv_mfma_kernel(const float* __restrict__ in, const f16* __restrict__ Wt,
                     const float* __restrict__ bq, const float* __restrict__ bk,
                     const float* __restrict__ bv,
                     f16* __restrict__ Qh, f16* __restrict__ Kf, f16* __restrict__ Vf)
{
  __shared__ __align__(16) char smem[32768];   // B dbuf (2x16KB); reused by epilogue
  const int m = blockIdx.y;
  const int tid = threadIdx.x, lane = tid & 63, w = tid >> 6;
  const int l15 = lane & 15, quad = lane >> 4;
  const int row0 = blockIdx.x * 64 + w * 16;
  const f16* Wm = Wt + ((size_t)m << 16);
  const float* bias = (m == 0) ? bq : (m == 1) ? bk : bv;

  // ---- A fragments: 16 rows of `in`, fp32 -> fp16 up front
  f16x8 af[8];
  {
    const float* arow = in + (size_t)(row0 + l15) * 768 + m * 256 + quad * 8;
#pragma unroll
    for (int kc = 0; kc < 8; ++kc) {
      float4 a0 = *(const float4*)(arow + kc * 32);
      float4 a1 = *(const float4*)(arow + kc * 32 + 4);
      f16x8 a;
      a[0] = (f16)a0.x; a[1] = (f16)a0.y; a[2] = (f16)a0.z; a[3] = (f16)a0.w;
      a[4] = (f16)a1.x; a[5] = (f16)a1.y; a[6] = (f16)a1.z; a[7] = (f16)a1.w;
      af[kc] = a;
    }
  }

  // ---- stage B(kc) into buffer: wave w stages ct = 4w..4w+3
  auto stageB = [&](int buf, int kc) {
    char* base = smem + buf * 16384;
#pragma unroll
    for (int i = 0; i < 4; ++i) {
      int ct = 4 * w + i;
      gll16(Wm + (ct * 16 + l15) * 256 + kc * 32 + quad * 8,
            base + ct * 1024 + lane * 16);
    }
  };

  f32x4 acc[16];
#pragma unroll
  for (int ct = 0; ct < 16; ++ct) acc[ct] = (f32x4){0.f, 0.f, 0.f, 0.f};

  stageB(0, 0);
  for (int kc = 0; kc < 8; ++kc) {
    __syncthreads();                       // B(kc) staged
    if (kc < 7) stageB((kc + 1) & 1, kc + 1);
    const char* Bb = smem + (kc & 1) * 16384;
#pragma unroll
    for (int ct = 0; ct < 16; ++ct) {
      f16x8 b = *(const f16x8*)(Bb + ct * 1024 + lane * 16);
      acc[ct] = MFMAH(af[kc], b, acc[ct]);
    }
  }
  __syncthreads();                         // B buffers dead; reuse for epilogue

  const int b_ = row0 >> 12;

  if (m == 0) {
    f16* ws = (f16*)(smem + w * 8192);
#pragma unroll
    for (int ct = 0; ct < 16; ++ct) {
      float bct = bias[ct * 16 + l15];
#pragma unroll
      for (int r = 0; r < 4; ++r)
        ws[(quad * 4 + r) * 256 + ct * 16 + l15] = (f16)((acc[ct][r] + bct) * SCALE);
    }
    f16* dst = Qh + (size_t)row0 * 256;
#pragma unroll
    for (int i = 0; i < 8; ++i)
      *(uint4*)(dst + lane * 8 + i * 512) = *(const uint4*)(ws + lane * 8 + i * 512);
  } else if (m == 1) {
    f16* ws = (f16*)(smem + w * 8192);
#pragma unroll
    for (int ct = 0; ct < 16; ++ct) {
      float bct = bias[ct * 16 + l15];
      int base = (ct >> 1) * 512 + ((ct & 1) * 2 + (l15 >> 3)) * 128 + (l15 & 7);
#pragma unroll
      for (int r = 0; r < 4; ++r)
        ws[base + (quad * 4 + r) * 8] = (f16)(acc[ct][r] + bct);
    }
    const int g = (row0 & 4095) >> 4;
    f16* dst = Kf + ((size_t)(b_ * 256 + g)) * 8 * 512;
#pragma unroll
    for (int i = 0; i < 8; ++i)
      *(uint4*)(dst + lane * 8 + i * 512) = *(const uint4*)(ws + lane * 8 + i * 512);
  } else {
    const int t = w & 1;
    f16* ws = (f16*)(smem + (w >> 1) * 16384);
#pragma unroll
    for (int ct = 0; ct < 16; ++ct) {
      float bct = bias[ct * 16 + l15];
      int base = ct * 512 + quad * 128 + l15 * 8 + t * 4;
#pragma unroll
      for (int r = 0; r < 4; ++r)
        ws[base + r] = (f16)(acc[ct][r] + bct);
    }
    __syncthreads();
    const int gv0 = ((blockIdx.x * 64) & 4095) >> 5;
    f16* dst = Vf + ((size_t)(b_ * 128 + gv0)) * 16 * 512;
    const f16* src = (const f16*)smem;
#pragma unroll
    for (int i = 0; i < 8; ++i)
      *(uint4*)(dst + tid * 8 + i * 2048) = *(const uint4*)(src + tid * 8 + i * 2048);
  }
}

// ---------------------------------------------------------------------------
// fp16 MFMA flash attention. 512 blocks x 256 thr, split-K=4, 32-key tiles.
// Round-1 changes: exp2-domain softmax (log2e folded into Q scale),
// defer-max (rescale only when tile max exceeds running max by >DTHR;
// mathematically exact, p bounded by 2^DTHR=64 in f16), and s_setprio(1)
// around the MFMA clusters (T5 — 2 desynced blocks/CU give role diversity).
// ---------------------------------------------------------------------------
__global__ __launch_bounds__(256, 2)
void attn6_kernel(const f16* __restrict__ Qh, const char* __restrict__ Kf,
                  const char* __restrict__ Vf,
                  f16* __restrict__ Pp, float* __restrict__ Mp, float* __restrict__ Lp)
{
  __shared__ __align__(16) char KVs[2][32768];   // [K 16 frags][V 16 frags]

  const int tid = threadIdx.x, lane = tid & 63, w = tid >> 6;
  const int l15 = lane & 15, quad = lane >> 4;

  const int bx    = blockIdx.x;
  const int combo = bx & 15;
  const int b     = combo & 3;
  const int kz    = combo >> 2;
  const int qb    = bx >> 4;                   // 0..31
  const int qrow0 = qb * 128 + w * 32;
  const int grow  = b * 4096 + qrow0;

  f16x8 qf[2][8];
#pragma unroll
  for (int sub = 0; sub < 2; ++sub) {
    const size_t qoff = (size_t)(grow + sub * 16 + l15) * 256 + quad * 8;
#pragma unroll
    for (int kc = 0; kc < 8; ++kc)
      qf[sub][kc] = *(const f16x8*)(Qh + qoff + kc * 32);
  }

  const char* kg[4];
  const char* vg[4];
#pragma unroll
  for (int i = 0; i < 4; ++i) {
    int f = 4 * w + i;
    kg[i] = Kf + (((size_t)(b * 256 + kz * 64 + (f >> 3))) * 8 + (f & 7)) * 1024
               + lane * 16;
    vg[i] = Vf + (((size_t)(b * 128 + kz * 32)) * 16 + f) * 1024 + lane * 16;
  }
  auto stage = [&](int buf) {
    char* base = &KVs[buf][0];
#pragma unroll
    for (int i = 0; i < 4; ++i) { gll16(kg[i], base + (4 * w + i) * 1024); kg[i] += 16384; }
#pragma unroll
    for (int i = 0; i < 4; ++i) { gll16(vg[i], base + 16384 + (4 * w + i) * 1024); vg[i] += 16384; }
  };

  f32x4 o0[16], o1[16];
#pragma unroll
  for (int ct = 0; ct < 16; ++ct) {
    o0[ct] = (f32x4){0.f, 0.f, 0.f, 0.f};
    o1[ct] = (f32x4){0.f, 0.f, 0.f, 0.f};
  }
  float m0 = -3.0e38f, m1 = -3.0e38f, l0 = 0.f, l1 = 0.f;

  stage(0);

  for (int it = 0; it < 32; ++it) {
    __syncthreads();
    if (it < 31) stage((it + 1) & 1);
    const char* Bf = &KVs[it & 1][0];

    f32x4 sA0 = (f32x4){0.f,0.f,0.f,0.f}, sB0 = (f32x4){0.f,0.f,0.f,0.f};
    f32x4 sA1 = (f32x4){0.f,0.f,0.f,0.f}, sB1 = (f32x4){0.f,0.f,0.f,0.f};
    __builtin_amdgcn_s_setprio(1);
#pragma unroll
    for (int kc = 0; kc < 8; ++kc) {
      f16x8 kA = *(const f16x8*)(Bf + kc * 1024 + lane * 16);
      f16x8 kB = *(const f16x8*)(Bf + 8192 + kc * 1024 + lane * 16);
      sA0 = MFMAH(kA, qf[0][kc], sA0);
      sA1 = MFMAH(kA, qf[1][kc], sA1);
      sB0 = MFMAH(kB, qf[0][kc], sB0);
      sB1 = MFMAH(kB, qf[1][kc], sB1);
    }
    __builtin_amdgcn_s_setprio(0);

    f16x8 ph0, ph1;
    {
      float t = fmaxf(fmaxf(fmaxf(sA0[0], sA0[1]), fmaxf(sA0[2], sA0[3])),
                      fmaxf(fmaxf(sB0[0], sB0[1]), fmaxf(sB0[2], sB0[3])));
      t = fmaxf(t, __shfl_xor(t, 16));
      t = fmaxf(t, __shfl_xor(t, 32));
      if (__any(t > m0 + DTHR)) {          // rare after iter 0 (defer-max)
        float mn = fmaxf(m0, t);
        float al = EX2(m0 - mn);
        float a0 = __shfl(al, (quad << 2) + 0);
        float a1 = __shfl(al, (quad << 2) + 1);
        float a2 = __shfl(al, (quad << 2) + 2);
        float a3 = __shfl(al, (quad << 2) + 3);
#pragma unroll
        for (int ct = 0; ct < 16; ++ct) {
          o0[ct][0] *= a0; o0[ct][1] *= a1; o0[ct][2] *= a2; o0[ct][3] *= a3;
        }
        l0 *= al;
        m0 = mn;
      }
      float ps = 0.f;
#pragma unroll
      for (int r = 0; r < 4; ++r) {
        float pa = EX2(sA0[r] - m0);
        float pb = EX2(sB0[r] - m0);
        ph0[r] = (f16)pa;  ph0[r + 4] = (f16)pb;
        ps += pa + pb;
      }
      ps += __shfl_xor(ps, 16);
      ps += __shfl_xor(ps, 32);
      l0 += ps;
    }
    {
      float t = fmaxf(fmaxf(fmaxf(sA1[0], sA1[1]), fmaxf(sA1[2], sA1[3])),
                      fmaxf(fmaxf(sB1[0], sB1[1]), fmaxf(sB1[2], sB1[3])));
      t = fmaxf(t, __shfl_xor(t, 16));
      t = fmaxf(t, __shfl_xor(t, 32));
      if (__any(t > m1 + DTHR)) {          // rare after iter 0 (defer-max)
        float mn = fmaxf(m1, t);
        float al = EX2(m1 - mn);
        float a0 = __shfl(al, (quad << 2) + 0);
        float a1 = __shfl(al, (quad << 2) + 1);
        float a2 = __shfl(al, (quad << 2) + 2);
        float a3 = __shfl(al, (quad << 2) + 3);
#pragma unroll
        for (int ct = 0; ct < 16; ++ct) {
          o1[ct][0] *= a0; o1[ct][1] *= a1; o1[ct][2] *= a2; o1[ct][3] *= a3;
        }
        l1 *= al;
        m1 = mn;
      }
      float ps = 0.f;
#pragma unroll
      for (int r = 0; r < 4; ++r) {
        float pa = EX2(sA1[r] - m1);
        float pb = EX2(sB1[r] - m1);
        ph1[r] = (f16)pa;  ph1[r + 4] = (f16)pb;
        ps += pa + pb;
      }
      ps += __shfl_xor(ps, 16);
      ps += __shfl_xor(ps, 32);
      l1 += ps;
    }

    __builtin_amdgcn_s_setprio(1);
#pragma unroll
    for (int ct = 0; ct < 16; ++ct) {
      f16x8 vf = *(const f16x8*)(Bf + 16384 + ct * 1024 + lane * 16);
      o0[ct] = MFMAH(ph0, vf, o0[ct]);
      o1[ct] = MFMAH(ph1, vf, o1[ct]);
    }
    __builtin_amdgcn_s_setprio(0);
  }

  f16* Od = Pp + (size_t)kz * NE;
#pragma unroll
  for (int r = 0; r < 4; ++r) {
    const size_t ro0 = (size_t)(grow + quad * 4 + r) * 256 + l15;
    const size_t ro1 = (size_t)(grow + 16 + quad * 4 + r) * 256 + l15;
#pragma unroll
    for (int ct = 0; ct < 16; ++ct) {
      Od[ro0 + ct * 16] = (f16)o0[ct][r];
      Od[ro1 + ct * 16] = (f16)o1[ct][r];
    }
  }
  if (lane < 16) {
    Mp[kz * NROWS + grow + l15] = m0;
    Lp[kz * NROWS + grow + l15] = l0;
    Mp[kz * NROWS + grow + 16 + l15] = m1;
    Lp[kz * NROWS + grow + 16 + l15] = l1;
  }
}

// ---------------------------------------------------------------------------
// Fused split-K merge + output projection. 512 blocks x 32 rows (2 blocks/CU).
// B tiles LDS-staged (dbuf, gll16). Wave w: rows (w&1)*16, cols (w>>1)*128.
// Merge weights in exp2 domain (matches attn's log2-unit m/l).
// ---------------------------------------------------------------------------
__global__ __launch_bounds__(256)
void oproj_mfma_kernel(const f16* __restrict__ Pp, const float* __restrict__ Mp,
                       const float* __restrict__ Lp, const f16* __restrict__ Wto,
                       const float* __restrict__ bo, float* __restrict__ out)
{
  __shared__ f16 xs[32][264];                   // 16.5 KB (padded)
  __shared__ __align__(16) char Bs[2][16384];   // 32 KB
  const int tid = threadIdx.x, lane = tid & 63, w = tid >> 6;
  const int l15 = lane & 15, quad = lane >> 4;
  const int rb = blockIdx.x * 32;

  auto stageB = [&](int buf, int kc) {
    char* base = &Bs[buf][0];
#pragma unroll
    for (int i = 0; i < 4; ++i) {
      int ct = 4 * w + i;
      gll16(Wto + (ct * 16 + l15) * 256 + kc * 32 + quad * 8,
            base + ct * 1024 + lane * 16);
    }
  };
  stageB(0, 0);

  // ---- merge prologue: 32 rows x 256 cols, 4-way split-K (exp2 domain)
  const int c4 = (tid & 63) * 4;
  const int rsub = tid >> 6;
#pragma unroll
  for (int e = 0; e < 8; ++e) {
    int rl = e * 4 + rsub;
    int row = rb + rl;
    float m[4], l[4];
#pragma unroll
    for (int z = 0; z < 4; ++z) {
      m[z] = Mp[z * NROWS + row];
      l[z] = Lp[z * NROWS + row];
    }
    float mm = fmaxf(fmaxf(m[0], m[1]), fmaxf(m[2], m[3]));
    float wz[4], denom = 0.f;
#pragma unroll
    for (int z = 0; z < 4; ++z) { wz[z] = EX2(m[z] - mm); denom += wz[z] * l[z]; }
    float inv = 1.0f / denom;
    float s0 = 0.f, s1 = 0.f, s2 = 0.f, s3 = 0.f;
#pragma unroll
    for (int z = 0; z < 4; ++z) {
      f16x4 h = *(const f16x4*)(Pp + (size_t)z * NE + (size_t)row * 256 + c4);
      s0 += wz[z] * (float)h[0];
      s1 += wz[z] * (float)h[1];
      s2 += wz[z] * (float)h[2];
      s3 += wz[z] * (float)h[3];
    }
    f16x4 xv;
    xv[0] = (f16)(s0 * inv); xv[1] = (f16)(s1 * inv);
    xv[2] = (f16)(s2 * inv); xv[3] = (f16)(s3 * inv);
    *(f16x4*)&xs[rl][c4] = xv;
  }

  // ---- GEMM: wave w -> rows (w&1)*16, ct group (w>>1)*8
  const int rw = (w & 1) * 16;
  const int cg = (w >> 1) * 8;
  f32x4 acc[8];
#pragma unroll
  for (int c = 0; c < 8; ++c) acc[c] = (f32x4){0.f, 0.f, 0.f, 0.f};

  for (int kc = 0; kc < 8; ++kc) {
    __syncthreads();                       // B(kc) staged (+ xs ready at kc=0)
    if (kc < 7) stageB((kc + 1) & 1, kc + 1);
    const char* Bb = &Bs[kc & 1][0];
    f16x8 a = *(const f16x8*)&xs[rw + l15][kc * 32 + quad * 8];
#pragma unroll
    for (int c = 0; c < 8; ++c) {
      f16x8 b = *(const f16x8*)(Bb + (cg + c) * 1024 + lane * 16);
      acc[c] = MFMAH(a, b, acc[c]);
    }
  }

#pragma unroll
  for (int c = 0; c < 8; ++c) {
    int col = (cg + c) * 16 + l15;
    float bct = bo[col];
#pragma unroll
    for (int r = 0; r < 4; ++r)
      out[(size_t)(rb + rw + quad * 4 + r) * 256 + col] = acc[c][r] + bct;
  }
}

// ---------------------------------------------------------------------------
extern "C" void kernel_launch(void* const* d_in, const int* in_sizes, int n_in,
                              void* d_out, int out_size, void* d_ws, size_t ws_size,
                              hipStream_t stream)
{
  const float* inp = (const float*)d_in[0];
  const float* wq  = (const float*)d_in[1];
  const float* bq  = (const float*)d_in[2];
  const float* wk  = (const float*)d_in[3];
  const float* bk  = (const float*)d_in[4];
  const float* wv  = (const float*)d_in[5];
  const float* bv  = (const float*)d_in[6];
  const float* wo  = (const float*)d_in[7];
  const float* bo  = (const float*)d_in[8];
  float* out = (float*)d_out;

  // ws (~60 MB): Qh, Kf, Vf (NE f16), Wt (4*65536 f16), Pp (4*NE f16), m/l
  f16* Qh = (f16*)d_ws;
  f16* Kf = Qh + NE;
  f16* Vf = Kf + NE;
  f16* Wt = Vf + NE;
  f16* Pp = Wt + 4 * 65536;
  float* Mp = (float*)(Pp + 4 * NE);
  float* Lp = Mp + 4 * NROWS;

  prep_wt_kernel<<<dim3(256, 4), 256, 0, stream>>>(wq, wk, wv, wo, Wt);

  qkv_mfma_kernel<<<dim3(256, 3), 256, 0, stream>>>(
      inp, Wt, bq, bk, bv, Qh, Kf, Vf);

  attn6_kernel<<<512, 256, 0, stream>>>(Qh, (const char*)Kf, (const char*)Vf,
                                        Pp, Mp, Lp);

  oproj_mfma_kernel<<<512, 256, 0, stream>>>(Pp, Mp, Lp, Wt + 3 * 65536, bo, out);
}

// Round 2
// 213.687 us; speedup vs baseline: 1.1369x; 1.0030x over previous
//
#include <hip/hip_runtime.h>

typedef _Float16 f16;
typedef _Float16 f16x4 __attribute__((ext_vector_type(4)));
typedef _Float16 f16x8 __attribute__((ext_vector_type(8)));
typedef float f32x4  __attribute__((ext_vector_type(4)));

#define MFMAH(a, b, c) __builtin_amdgcn_mfma_f32_16x16x32_f16(a, b, c, 0, 0, 0)
#define EX2(x) __builtin_amdgcn_exp2f(x)

constexpr int D = 256;
constexpr int S = 4096;
constexpr int BATCH = 4;
constexpr int NROWS = BATCH * S;           // 16384
// softmax runs in exp2 domain: fold log2(e) into the Q scale.
constexpr float SCALE = 0.0625f * 1.44269504088896340736f;
constexpr float DTHR = 6.0f;               // defer-max threshold (log2 units): p <= 64
constexpr size_t NE = (size_t)NROWS * D;   // 4.19M elems

// async global->LDS: per-lane src addr, wave-uniform LDS base (+lane*16 by HW)
__device__ __forceinline__ void gll16(const void* g, void* l) {
  __builtin_amdgcn_global_load_lds(
      (const __attribute__((address_space(1))) unsigned int*)g,
      (__attribute__((address_space(3))) unsigned int*)l, 16, 0, 0);
}

// ---------------------------------------------------------------------------
// Prep: W in MFMA-fragment order. frag f = ct*8+kc (1KB each), lane-contiguous:
// Wf[m][f][lane][j] = w_m[(kc*32+quad*8+j)][ct*16+l15]   (fp16)
// A wave's B-fragment read is then ONE coalesced 1KB global_load_dwordx4
// (L2-resident, 128KB/m) -> qkv/oproj need no LDS staging and no barriers.
// ---------------------------------------------------------------------------
__global__ __launch_bounds__(256)
void prep_wt_kernel(const float* __restrict__ wq, const float* __restrict__ wk,
                    const float* __restrict__ wv, const float* __restrict__ wo,
                    f16* __restrict__ Wf)
{
  const int m = blockIdx.y;
  const float* w = (m == 0) ? wq : (m == 1) ? wk : (m == 2) ? wv : wo;
  int id = blockIdx.x * 256 + threadIdx.x;    // 0..8191 (one 16B chunk each)
  int f = id >> 6, lane = id & 63;
  int ct = f >> 3, kc = f & 7;
  int l15 = lane & 15, quad = lane >> 4;
  const float* src = w + (kc * 32 + quad * 8) * 256 + ct * 16 + l15;
  f16x8 v;
#pragma unroll
  for (int j = 0; j < 8; ++j) v[j] = (f16)src[j * 256];
  *(f16x8*)(Wf + ((size_t)m << 16) + (size_t)id * 8) = v;
}

// ---------------------------------------------------------------------------
// QKV projection via MFMA. B fragments read directly from L2 (fragment-ordered
// Wf) -> barrier-free main loop, fully compiler-pipelined. LDS used only for
// the transposed coalesced epilogues (r7-validated layouts).
// Q: row-major fp16, scaled by SCALE (exp2-domain softmax downstream).
// ---------------------------------------------------------------------------
__global__ __launch_bounds__(256)
void qkv_mfma_kernel(const float* __restrict__ in, const f16* __restrict__ Wt,
                     const float* __restrict__ bq, const float* __restrict__ bk,
                     const float* __restrict__ bv,
                     f16* __restrict__ Qh, f16* __restrict__ Kf, f16* __restrict__ Vf)
{
  __shared__ __align__(16) char smem[32768];   // epilogue transpose buffer
  const int m = blockIdx.y;
  const int tid = threadIdx.x, lane = tid & 63, w = tid >> 6;
  const int l15 = lane & 15, quad = lane >> 4;
  const int row0 = blockIdx.x * 64 + w * 16;
  const f16* Wm = Wt + ((size_t)m << 16);
  const float* bias = (m == 0) ? bq : (m == 1) ? bk : bv;

  // ---- A fragments: 16 rows of `in`, fp32 -> fp16 up front
  f16x8 af[8];
  {
    const float* arow = in + (size_t)(row0 + l15) * 768 + m * 256 + quad * 8;
#pragma unroll
    for (int kc = 0; kc < 8; ++kc) {
      float4 a0 = *(const float4*)(arow + kc * 32);
      float4 a1 = *(const float4*)(arow + kc * 32 + 4);
      f16x8 a;
      a[0] = (f16)a0.x; a[1] = (f16)a0.y; a[2] = (f16)a0.z; a[3] = (f16)a0.w;
      a[4] = (f16)a1.x; a[5] = (f16)a1.y; a[6] = (f16)a1.z; a[7] = (f16)a1.w;
      af[kc] = a;
    }
  }

  f32x4 acc[16];
#pragma unroll
  for (int ct = 0; ct < 16; ++ct) acc[ct] = (f32x4){0.f, 0.f, 0.f, 0.f};

  // ---- main loop: direct L2 B-frag loads, no barriers
#pragma unroll
  for (int kc = 0; kc < 8; ++kc) {
#pragma unroll
    for (int ct = 0; ct < 16; ++ct) {
      f16x8 b = *(const f16x8*)(Wm + (size_t)(ct * 8 + kc) * 512 + lane * 8);
      acc[ct] = MFMAH(af[kc], b, acc[ct]);
    }
  }

  const int b_ = row0 >> 12;

  if (m == 0) {
    f16* ws = (f16*)(smem + w * 8192);
#pragma unroll
    for (int ct = 0; ct < 16; ++ct) {
      float bct = bias[ct * 16 + l15];
#pragma unroll
      for (int r = 0; r < 4; ++r)
        ws[(quad * 4 + r) * 256 + ct * 16 + l15] = (f16)((acc[ct][r] + bct) * SCALE);
    }
    f16* dst = Qh + (size_t)row0 * 256;
#pragma unroll
    for (int i = 0; i < 8; ++i)
      *(uint4*)(dst + lane * 8 + i * 512) = *(const uint4*)(ws + lane * 8 + i * 512);
  } else if (m == 1) {
    f16* ws = (f16*)(smem + w * 8192);
#pragma unroll
    for (int ct = 0; ct < 16; ++ct) {
      float bct = bias[ct * 16 + l15];
      int base = (ct >> 1) * 512 + ((ct & 1) * 2 + (l15 >> 3)) * 128 + (l15 & 7);
#pragma unroll
      for (int r = 0; r < 4; ++r)
        ws[base + (quad * 4 + r) * 8] = (f16)(acc[ct][r] + bct);
    }
    const int g = (row0 & 4095) >> 4;
    f16* dst = Kf + ((size_t)(b_ * 256 + g)) * 8 * 512;
#pragma unroll
    for (int i = 0; i < 8; ++i)
      *(uint4*)(dst + lane * 8 + i * 512) = *(const uint4*)(ws + lane * 8 + i * 512);
  } else {
    const int t = w & 1;
    f16* ws = (f16*)(smem + (w >> 1) * 16384);
#pragma unroll
    for (int ct = 0; ct < 16; ++ct) {
      float bct = bias[ct * 16 + l15];
      int base = ct * 512 + quad * 128 + l15 * 8 + t * 4;
#pragma unroll
      for (int r = 0; r < 4; ++r)
        ws[base + r] = (f16)(acc[ct][r] + bct);
    }
    __syncthreads();
    const int gv0 = ((blockIdx.x * 64) & 4095) >> 5;
    f16* dst = Vf + ((size_t)(b_ * 128 + gv0)) * 16 * 512;
    const f16* src = (const f16*)smem;
#pragma unroll
    for (int i = 0; i < 8; ++i)
      *(uint4*)(dst + tid * 8 + i * 2048) = *(const uint4*)(src + tid * 8 + i * 2048);
  }
}

// ---------------------------------------------------------------------------
// fp16 MFMA flash attention. 512 blocks x 256 thr, split-K=4, 32-key tiles.
// exp2-domain softmax (log2e folded into Q scale), defer-max (rescale only
// when tile max exceeds running max by >DTHR; exact, p bounded by 2^DTHR=64),
// s_setprio(1) around MFMA clusters. (Round-1 verified: 86.7us)
// ---------------------------------------------------------------------------
__global__ __launch_bounds__(256, 2)
void attn6_kernel(const f16* __restrict__ Qh, const char* __restrict__ Kf,
                  const char* __restrict__ Vf,
                  f16* __restrict__ Pp, float* __restrict__ Mp, float* __restrict__ Lp)
{
  __shared__ __align__(16) char KVs[2][32768];   // [K 16 frags][V 16 frags]

  const int tid = threadIdx.x, lane = tid & 63, w = tid >> 6;
  const int l15 = lane & 15, quad = lane >> 4;

  const int bx    = blockIdx.x;
  const int combo = bx & 15;
  const int b     = combo & 3;
  const int kz    = combo >> 2;
  const int qb    = bx >> 4;                   // 0..31
  const int qrow0 = qb * 128 + w * 32;
  const int grow  = b * 4096 + qrow0;

  f16x8 qf[2][8];
#pragma unroll
  for (int sub = 0; sub < 2; ++sub) {
    const size_t qoff = (size_t)(grow + sub * 16 + l15) * 256 + quad * 8;
#pragma unroll
    for (int kc = 0; kc < 8; ++kc)
      qf[sub][kc] = *(const f16x8*)(Qh + qoff + kc * 32);
  }

  const char* kg[4];
  const char* vg[4];
#pragma unroll
  for (int i = 0; i < 4; ++i) {
    int f = 4 * w + i;
    kg[i] = Kf + (((size_t)(b * 256 + kz * 64 + (f >> 3))) * 8 + (f & 7)) * 1024
               + lane * 16;
    vg[i] = Vf + (((size_t)(b * 128 + kz * 32)) * 16 + f) * 1024 + lane * 16;
  }
  auto stage = [&](int buf) {
    char* base = &KVs[buf][0];
#pragma unroll
    for (int i = 0; i < 4; ++i) { gll16(kg[i], base + (4 * w + i) * 1024); kg[i] += 16384; }
#pragma unroll
    for (int i = 0; i < 4; ++i) { gll16(vg[i], base + 16384 + (4 * w + i) * 1024); vg[i] += 16384; }
  };

  f32x4 o0[16], o1[16];
#pragma unroll
  for (int ct = 0; ct < 16; ++ct) {
    o0[ct] = (f32x4){0.f, 0.f, 0.f, 0.f};
    o1[ct] = (f32x4){0.f, 0.f, 0.f, 0.f};
  }
  float m0 = -3.0e38f, m1 = -3.0e38f, l0 = 0.f, l1 = 0.f;

  stage(0);

  for (int it = 0; it < 32; ++it) {
    __syncthreads();
    if (it < 31) stage((it + 1) & 1);
    const char* Bf = &KVs[it & 1][0];

    f32x4 sA0 = (f32x4){0.f,0.f,0.f,0.f}, sB0 = (f32x4){0.f,0.f,0.f,0.f};
    f32x4 sA1 = (f32x4){0.f,0.f,0.f,0.f}, sB1 = (f32x4){0.f,0.f,0.f,0.f};
    __builtin_amdgcn_s_setprio(1);
#pragma unroll
    for (int kc = 0; kc < 8; ++kc) {
      f16x8 kA = *(const f16x8*)(Bf + kc * 1024 + lane * 16);
      f16x8 kB = *(const f16x8*)(Bf + 8192 + kc * 1024 + lane * 16);
      sA0 = MFMAH(kA, qf[0][kc], sA0);
      sA1 = MFMAH(kA, qf[1][kc], sA1);
      sB0 = MFMAH(kB, qf[0][kc], sB0);
      sB1 = MFMAH(kB, qf[1][kc], sB1);
    }
    __builtin_amdgcn_s_setprio(0);

    f16x8 ph0, ph1;
    {
      float t = fmaxf(fmaxf(fmaxf(sA0[0], sA0[1]), fmaxf(sA0[2], sA0[3])),
                      fmaxf(fmaxf(sB0[0], sB0[1]), fmaxf(sB0[2], sB0[3])));
      t = fmaxf(t, __shfl_xor(t, 16));
      t = fmaxf(t, __shfl_xor(t, 32));
      if (__any(t > m0 + DTHR)) {          // rare after iter 0 (defer-max)
        float mn = fmaxf(m0, t);
        float al = EX2(m0 - mn);
        float a0 = __shfl(al, (quad << 2) + 0);
        float a1 = __shfl(al, (quad << 2) + 1);
        float a2 = __shfl(al, (quad << 2) + 2);
        float a3 = __shfl(al, (quad << 2) + 3);
#pragma unroll
        for (int ct = 0; ct < 16; ++ct) {
          o0[ct][0] *= a0; o0[ct][1] *= a1; o0[ct][2] *= a2; o0[ct][3] *= a3;
        }
        l0 *= al;
        m0 = mn;
      }
      float ps = 0.f;
#pragma unroll
      for (int r = 0; r < 4; ++r) {
        float pa = EX2(sA0[r] - m0);
        float pb = EX2(sB0[r] - m0);
        ph0[r] = (f16)pa;  ph0[r + 4] = (f16)pb;
        ps += pa + pb;
      }
      ps += __shfl_xor(ps, 16);
      ps += __shfl_xor(ps, 32);
      l0 += ps;
    }
    {
      float t = fmaxf(fmaxf(fmaxf(sA1[0], sA1[1]), fmaxf(sA1[2], sA1[3])),
                      fmaxf(fmaxf(sB1[0], sB1[1]), fmaxf(sB1[2], sB1[3])));
      t = fmaxf(t, __shfl_xor(t, 16));
      t = fmaxf(t, __shfl_xor(t, 32));
      if (__any(t > m1 + DTHR)) {          // rare after iter 0 (defer-max)
        float mn = fmaxf(m1, t);
        float al = EX2(m1 - mn);
        float a0 = __shfl(al, (quad << 2) + 0);
        float a1 = __shfl(al, (quad << 2) + 1);
        float a2 = __shfl(al, (quad << 2) + 2);
        float a3 = __shfl(al, (quad << 2) + 3);
#pragma unroll
        for (int ct = 0; ct < 16; ++ct) {
          o1[ct][0] *= a0; o1[ct][1] *= a1; o1[ct][2] *= a2; o1[ct][3] *= a3;
        }
        l1 *= al;
        m1 = mn;
      }
      float ps = 0.f;
#pragma unroll
      for (int r = 0; r < 4; ++r) {
        float pa = EX2(sA1[r] - m1);
        float pb = EX2(sB1[r] - m1);
        ph1[r] = (f16)pa;  ph1[r + 4] = (f16)pb;
        ps += pa + pb;
      }
      ps += __shfl_xor(ps, 16);
      ps += __shfl_xor(ps, 32);
      l1 += ps;
    }

    __builtin_amdgcn_s_setprio(1);
#pragma unroll
    for (int ct = 0; ct < 16; ++ct) {
      f16x8 vf = *(const f16x8*)(Bf + 16384 + ct * 1024 + lane * 16);
      o0[ct] = MFMAH(ph0, vf, o0[ct]);
      o1[ct] = MFMAH(ph1, vf, o1[ct]);
    }
    __builtin_amdgcn_s_setprio(0);
  }

  f16* Od = Pp + (size_t)kz * NE;
#pragma unroll
  for (int r = 0; r < 4; ++r) {
    const size_t ro0 = (size_t)(grow + quad * 4 + r) * 256 + l15;
    const size_t ro1 = (size_t)(grow + 16 + quad * 4 + r) * 256 + l15;
#pragma unroll
    for (int ct = 0; ct < 16; ++ct) {
      Od[ro0 + ct * 16] = (f16)o0[ct][r];
      Od[ro1 + ct * 16] = (f16)o1[ct][r];
    }
  }
  if (lane < 16) {
    Mp[kz * NROWS + grow + l15] = m0;
    Lp[kz * NROWS + grow + l15] = l0;
    Mp[kz * NROWS + grow + 16 + l15] = m1;
    Lp[kz * NROWS + grow + 16 + l15] = l1;
  }
}

// ---------------------------------------------------------------------------
// Fused split-K merge + output projection. 512 blocks x 32 rows.
// B fragments read directly from L2 (fragment-ordered Wf) -> single barrier
// (merge->GEMM); no staging. Merge weights in exp2 domain.
// ---------------------------------------------------------------------------
__global__ __launch_bounds__(256)
void oproj_mfma_kernel(const f16* __restrict__ Pp, const float* __restrict__ Mp,
                       const float* __restrict__ Lp, const f16* __restrict__ Wto,
                       const float* __restrict__ bo, float* __restrict__ out)
{
  __shared__ f16 xs[32][264];                   // 16.5 KB (padded)
  const int tid = threadIdx.x, lane = tid & 63, w = tid >> 6;
  const int l15 = lane & 15, quad = lane >> 4;
  const int rb = blockIdx.x * 32;

  // ---- merge prologue: 32 rows x 256 cols, 4-way split-K (exp2 domain)
  const int c4 = (tid & 63) * 4;
  const int rsub = tid >> 6;
#pragma unroll
  for (int e = 0; e < 8; ++e) {
    int rl = e * 4 + rsub;
    int row = rb + rl;
    float m[4], l[4];
#pragma unroll
    for (int z = 0; z < 4; ++z) {
      m[z] = Mp[z * NROWS + row];
      l[z] = Lp[z * NROWS + row];
    }
    float mm = fmaxf(fmaxf(m[0], m[1]), fmaxf(m[2], m[3]));
    float wz[4], denom = 0.f;
#pragma unroll
    for (int z = 0; z < 4; ++z) { wz[z] = EX2(m[z] - mm); denom += wz[z] * l[z]; }
    float inv = 1.0f / denom;
    float s0 = 0.f, s1 = 0.f, s2 = 0.f, s3 = 0.f;
#pragma unroll
    for (int z = 0; z < 4; ++z) {
      f16x4 h = *(const f16x4*)(Pp + (size_t)z * NE + (size_t)row * 256 + c4);
      s0 += wz[z] * (float)h[0];
      s1 += wz[z] * (float)h[1];
      s2 += wz[z] * (float)h[2];
      s3 += wz[z] * (float)h[3];
    }
    f16x4 xv;
    xv[0] = (f16)(s0 * inv); xv[1] = (f16)(s1 * inv);
    xv[2] = (f16)(s2 * inv); xv[3] = (f16)(s3 * inv);
    *(f16x4*)&xs[rl][c4] = xv;
  }
  __syncthreads();                       // xs ready

  // ---- GEMM: wave w -> rows (w&1)*16, ct group (w>>1)*8; B frags from L2
  const int rw = (w & 1) * 16;
  const int cg = (w >> 1) * 8;
  f32x4 acc[8];
#pragma unroll
  for (int c = 0; c < 8; ++c) acc[c] = (f32x4){0.f, 0.f, 0.f, 0.f};

#pragma unroll
  for (int kc = 0; kc < 8; ++kc) {
    f16x8 a = *(const f16x8*)&xs[rw + l15][kc * 32 + quad * 8];
#pragma unroll
    for (int c = 0; c < 8; ++c) {
      f16x8 b = *(const f16x8*)(Wto + (size_t)((cg + c) * 8 + kc) * 512 + lane * 8);
      acc[c] = MFMAH(a, b, acc[c]);
    }
  }

#pragma unroll
  for (int c = 0; c < 8; ++c) {
    int col = (cg + c) * 16 + l15;
    float bct = bo[col];
#pragma unroll
    for (int r = 0; r < 4; ++r)
      out[(size_t)(rb + rw + quad * 4 + r) * 256 + col] = acc[c][r] + bct;
  }
}

// ---------------------------------------------------------------------------
extern "C" void kernel_launch(void* const* d_in, const int* in_sizes, int n_in,
                              void* d_out, int out_size, void* d_ws, size_t ws_size,
                              hipStream_t stream)
{
  const float* inp = (const float*)d_in[0];
  const float* wq  = (const float*)d_in[1];
  const float* bq  = (const float*)d_in[2];
  const float* wk  = (const float*)d_in[3];
  const float* bk  = (const float*)d_in[4];
  const float* wv  = (const float*)d_in[5];
  const float* bv  = (const float*)d_in[6];
  const float* wo  = (const float*)d_in[7];
  const float* bo  = (const float*)d_in[8];
  float* out = (float*)d_out;

  // ws (~60 MB): Qh, Kf, Vf (NE f16), Wt (4*65536 f16 frag-ordered), Pp, m/l
  f16* Qh = (f16*)d_ws;
  f16* Kf = Qh + NE;
  f16* Vf = Kf + NE;
  f16* Wt = Vf + NE;
  f16* Pp = Wt + 4 * 65536;
  float* Mp = (float*)(Pp + 4 * NE);
  float* Lp = Mp + 4 * NROWS;

  prep_wt_kernel<<<dim3(32, 4), 256, 0, stream>>>(wq, wk, wv, wo, Wt);

  qkv_mfma_kernel<<<dim3(256, 3), 256, 0, stream>>>(
      inp, Wt, bq, bk, bv, Qh, Kf, Vf);

  attn6_kernel<<<512, 256, 0, stream>>>(Qh, (const char*)Kf, (const char*)Vf,
                                        Pp, Mp, Lp);

  oproj_mfma_kernel<<<512, 256, 0, stream>>>(Pp, Mp, Lp, Wt + 3 * 65536, bo, out);
}